// Round 19
// baseline (1499.630 us; speedup 1.0000x reference)
//
#include <hip/hip_runtime.h>
#include <hip/hip_bf16.h>
#include <math.h>

#define V_ 50257
#define L_ 6
#define H_ 12
#define D_ 768
#define HD_ 64
#define FF_ 3072
#define B_ 2
#define T_ 1024
#define NTOK (B_*T_)
#define EOS_ 50256
#define QBLK 64
#define KVB 64
#define NS2 393            // number of 128-col logit tiles
#define QS3 (3*D_)         // qkv row stride in elements

typedef __attribute__((ext_vector_type(8))) short s16x8;
typedef __attribute__((ext_vector_type(4))) float f32x4;

__device__ __forceinline__ short f2bf(float f) {
  __hip_bfloat16 h = __float2bfloat16(f);
  return *reinterpret_cast<short*>(&h);
}

// async global->LDS, 16B per lane; l must be the WAVE-uniform base (HW adds lane*16)
__device__ __forceinline__ void gl_lds16(const void* g, void* l) {
  __builtin_amdgcn_global_load_lds(
      (const __attribute__((address_space(1))) unsigned int*)g,
      (__attribute__((address_space(3))) unsigned int*)l, 16, 0, 0);
}

// ---------------- embedding ----------------
__global__ void k_embed(const int* __restrict__ idx, const float* __restrict__ tok,
                        const float* __restrict__ pos, float* __restrict__ x) {
  int gid = blockIdx.x * blockDim.x + threadIdx.x;
  const int total = NTOK * D_;
  if (gid >= total) return;
  int row = gid / D_;
  int d = gid - row * D_;
  int t = row & (T_ - 1);
  x[gid] = tok[(size_t)idx[row] * D_ + d] + pos[t * D_ + d];
}

// ---------------- doc ids ----------------
__global__ void k_docid(const int* __restrict__ idx, int* __restrict__ doc) {
  int b = threadIdx.x;
  if (b >= B_) return;
  int c = 0;
  for (int t = 0; t < T_; ++t) {
    int e = (idx[b*T_ + t] == EOS_) ? 1 : 0;
    doc[b*T_ + t] = c;
    c += e;
  }
}

// ---------------- tok f32 -> bf16 cast --------
__global__ void k_cast_tok(const float* __restrict__ in,
                           __hip_bfloat16* __restrict__ out, long n8) {
  long i = (long)blockIdx.x*blockDim.x + threadIdx.x;
  long stride = (long)gridDim.x*blockDim.x;
  for (; i < n8; i += stride) {
    const float4* src = (const float4*)(in + i*8);
    float4 v0 = src[0], v1 = src[1];
    s16x8 s;
    s[0]=f2bf(v0.x); s[1]=f2bf(v0.y); s[2]=f2bf(v0.z); s[3]=f2bf(v0.w);
    s[4]=f2bf(v1.x); s[5]=f2bf(v1.y); s[6]=f2bf(v1.z); s[7]=f2bf(v1.w);
    *(s16x8*)((short*)out + i*8) = s;
  }
}

// ---------------- layernorm ----------------
__global__ void k_ln(const float* __restrict__ x, const float* __restrict__ g,
                     const float* __restrict__ b, __hip_bfloat16* __restrict__ out) {
  int row = blockIdx.x;
  const float* xr = x + (size_t)row * D_;
  int lane = threadIdx.x;
  float vals[D_/64];
  float s = 0.f;
  #pragma unroll
  for (int i = 0; i < D_/64; ++i) { vals[i] = xr[lane + i*64]; s += vals[i]; }
  #pragma unroll
  for (int o = 1; o < 64; o <<= 1) s += __shfl_xor(s, o);
  float mu = s * (1.f/D_);
  float v = 0.f;
  #pragma unroll
  for (int i = 0; i < D_/64; ++i) { float d0 = vals[i]-mu; v += d0*d0; }
  #pragma unroll
  for (int o = 1; o < 64; o <<= 1) v += __shfl_xor(v, o);
  float inv = rsqrtf(v * (1.f/D_) + 1e-5f);
  #pragma unroll
  for (int i = 0; i < D_/64; ++i) {
    int d = lane + i*64;
    out[(size_t)row*D_ + d] = __float2bfloat16((vals[i]-mu)*inv*g[d] + b[d]);
  }
}

// ------- weight transpose+cast -------
__global__ void k_wt(const float* __restrict__ in, __hip_bfloat16* __restrict__ out,
                     int K, int N) {
  __shared__ float tile[32][33];
  int l = blockIdx.z;
  const float* src = in + (size_t)l*K*N;
  __hip_bfloat16* dst = out + (size_t)l*N*K;
  int n0 = blockIdx.x*32, k0 = blockIdx.y*32;
  int tx = threadIdx.x, ty = threadIdx.y;
  #pragma unroll
  for (int i = 0; i < 4; ++i)
    tile[ty + i*8][tx] = src[(size_t)(k0 + ty + i*8)*N + n0 + tx];
  __syncthreads();
  #pragma unroll
  for (int i = 0; i < 4; ++i)
    dst[(size_t)(n0 + ty + i*8)*K + k0 + tx] = __float2bfloat16(tile[tx][ty + i*8]);
}

// ------- MFMA NT GEMM (128x128x64), 512 thr, dbuf + counted-vmcnt pipeline -------
__global__ __launch_bounds__(512) void k_mfma_nt(
    const __hip_bfloat16* __restrict__ A,
    const __hip_bfloat16* __restrict__ Bh,
    const float* __restrict__ Bf,
    const float* __restrict__ bias,
    const float* resid,
    float* outf, __hip_bfloat16* outh,
    int M, int N, int K, int gelu)
{
  __shared__ __align__(16) short lds_a[2][128*64];
  __shared__ __align__(16) short lds_b[2][128*64];
  const int t = threadIdx.x;
  const int m0 = blockIdx.y * 128;
  const int n0 = blockIdx.x * 128;
  const int lane = t & 63;
  const int wid = t >> 6;
  const int wm = (wid >> 2) * 64;
  const int wn = (wid & 3) * 32;
  const int lrow = lane & 15;
  const int lkb = (lane >> 4) * 16;
  const int wbase = (t & 448) * 16;

  auto stageA = [&](int buf, int k0) {
    #pragma unroll
    for (int p = 0; p < 2; ++p) {
      int c = p*512 + t;
      int row = c >> 3;
      int colb = (c & 7) << 4;
      const char* src = (const char*)A + ((size_t)(m0+row)*K + k0)*2 + (colb ^ ((row & 7) << 4));
      gl_lds16(src, (char*)lds_a[buf] + p*8192 + wbase);
    }
  };
  auto stageB = [&](int buf, int k0) {
    if (Bh) {
      #pragma unroll
      for (int p = 0; p < 2; ++p) {
        int c = p*512 + t;
        int row = c >> 3;
        int colb = (c & 7) << 4;
        const char* src = (const char*)Bh + ((size_t)(n0+row)*K + k0)*2 + (colb ^ ((row & 7) << 4));
        gl_lds16(src, (char*)lds_b[buf] + p*8192 + wbase);
      }
    } else {
      #pragma unroll
      for (int p = 0; p < 2; ++p) {
        int c = p*512 + t;
        int row = c >> 3;
        int colb = (c & 7) << 4;
        int gn = n0 + row;
        s16x8 s = {0,0,0,0,0,0,0,0};
        if (gn < N) {
          const char* src = (const char*)Bf + ((size_t)gn*K + k0)*4 + colb*2;
          float4 v0 = *(const float4*)src;
          float4 v1 = *(const float4*)(src + 16);
          s[0]=f2bf(v0.x); s[1]=f2bf(v0.y); s[2]=f2bf(v0.z); s[3]=f2bf(v0.w);
          s[4]=f2bf(v1.x); s[5]=f2bf(v1.y); s[6]=f2bf(v1.z); s[7]=f2bf(v1.w);
        }
        int dst = (row*128 + colb) ^ ((row & 7) << 4);
        *(s16x8*)((char*)lds_b[buf] + dst) = s;
      }
    }
  };

  f32x4 acc[4][2];
  #pragma unroll
  for (int i = 0; i < 4; ++i)
    #pragma unroll
    for (int j = 0; j < 2; ++j)
      acc[i][j] = (f32x4){0.f, 0.f, 0.f, 0.f};

  const int nk = K >> 6;
  stageA(0, 0); stageB(0, 0);
  stageA(1, 64); stageB(1, 64);
  const bool piped = (Bh != nullptr);
  for (int kt = 0; kt < nk; ++kt) {
    if (piped && kt + 1 < nk) asm volatile("s_waitcnt vmcnt(4)" ::: "memory");
    else                      asm volatile("s_waitcnt vmcnt(0) lgkmcnt(0)" ::: "memory");
    __builtin_amdgcn_s_barrier();
    const int cur = kt & 1;
    #pragma unroll
    for (int ks = 0; ks < 2; ++ks) {
      s16x8 af[4], bfr[2];
      #pragma unroll
      for (int f = 0; f < 4; ++f) {
        int row = wm + f*16 + lrow;
        int off = (row*128 + ks*64 + lkb) ^ ((row & 7) << 4);
        af[f] = *(const s16x8*)((const char*)lds_a[cur] + off);
      }
      #pragma unroll
      for (int f = 0; f < 2; ++f) {
        int row = wn + f*16 + lrow;
        int off = (row*128 + ks*64 + lkb) ^ ((row & 7) << 4);
        bfr[f] = *(const s16x8*)((const char*)lds_b[cur] + off);
      }
      #pragma unroll
      for (int fm = 0; fm < 4; ++fm)
        #pragma unroll
        for (int fn = 0; fn < 2; ++fn)
          acc[fm][fn] = __builtin_amdgcn_mfma_f32_16x16x32_bf16(
              af[fm], bfr[fn], acc[fm][fn], 0, 0, 0);
    }
    __builtin_amdgcn_s_barrier();
    if (kt + 2 < nk) { stageA(cur, (kt+2)*64); stageB(cur, (kt+2)*64); }
  }
  const int crow = (lane >> 4) * 4;
  #pragma unroll
  for (int fm = 0; fm < 4; ++fm) {
    #pragma unroll
    for (int fn = 0; fn < 2; ++fn) {
      int col = n0 + wn + fn*16 + lrow;
      if (col >= N) continue;
      #pragma unroll
      for (int r = 0; r < 4; ++r) {
        int row = m0 + wm + fm*16 + crow + r;
        float v = acc[fm][fn][r];
        if (bias) v += bias[col];
        if (gelu) v = 0.5f * v * (1.f + erff(v * 0.70710678118654752f));
        if (resid) v += resid[(size_t)row*N + col];
        if (outf) outf[(size_t)row*N + col] = v;
        else      outh[(size_t)row*N + col] = __float2bfloat16(v);
      }
    }
  }
}

// ------- small-N MFMA NT GEMM (64x64x64): proj, fc2 — dbuf counted-vmcnt -------
__global__ __launch_bounds__(256) void k_mfma_nt64(
    const __hip_bfloat16* __restrict__ A,
    const __hip_bfloat16* __restrict__ Bh,
    const float* __restrict__ bias,
    const float* resid,
    float* outf,
    int M, int N, int K)
{
  __shared__ __align__(16) short lds_a[2][64*64];
  __shared__ __align__(16) short lds_b[2][64*64];
  const int t = threadIdx.x;
  const int m0 = blockIdx.y * 64;
  const int n0 = blockIdx.x * 64;
  const int lane = t & 63;
  const int wid = t >> 6;
  const int wm = (wid >> 1) * 32;
  const int wn = (wid & 1) * 32;
  const int lrow = lane & 15;
  const int lkb = (lane >> 4) * 16;
  const int wbase = (t & 192) * 16;

  auto stage = [&](int buf, int k0) {
    #pragma unroll
    for (int p = 0; p < 2; ++p) {
      int c = p*256 + t;
      int row = c >> 3;
      int colb = (c & 7) << 4;
      const char* srcA = (const char*)A + ((size_t)(m0+row)*K + k0)*2 + (colb ^ ((row & 7) << 4));
      gl_lds16(srcA, (char*)lds_a[buf] + p*4096 + wbase);
    }
    #pragma unroll
    for (int p = 0; p < 2; ++p) {
      int c = p*256 + t;
      int row = c >> 3;
      int colb = (c & 7) << 4;
      const char* srcB = (const char*)Bh + ((size_t)(n0+row)*K + k0)*2 + (colb ^ ((row & 7) << 4));
      gl_lds16(srcB, (char*)lds_b[buf] + p*4096 + wbase);
    }
  };

  f32x4 acc[2][2];
  #pragma unroll
  for (int i = 0; i < 2; ++i)
    #pragma unroll
    for (int j = 0; j < 2; ++j)
      acc[i][j] = (f32x4){0.f, 0.f, 0.f, 0.f};

  const int nk = K >> 6;
  stage(0, 0);
  stage(1, 64);
  for (int kt = 0; kt < nk; ++kt) {
    if (kt + 1 < nk) asm volatile("s_waitcnt vmcnt(4)" ::: "memory");
    else             asm volatile("s_waitcnt vmcnt(0)" ::: "memory");
    __builtin_amdgcn_s_barrier();
    const int cur = kt & 1;
    #pragma unroll
    for (int ks = 0; ks < 2; ++ks) {
      s16x8 af[2], bfr[2];
      #pragma unroll
      for (int f = 0; f < 2; ++f) {
        int row = wm + f*16 + lrow;
        int off = (row*128 + ks*64 + lkb) ^ ((row & 7) << 4);
        af[f] = *(const s16x8*)((const char*)lds_a[cur] + off);
      }
      #pragma unroll
      for (int f = 0; f < 2; ++f) {
        int row = wn + f*16 + lrow;
        int off = (row*128 + ks*64 + lkb) ^ ((row & 7) << 4);
        bfr[f] = *(const s16x8*)((const char*)lds_b[cur] + off);
      }
      #pragma unroll
      for (int fm = 0; fm < 2; ++fm)
        #pragma unroll
        for (int fn = 0; fn < 2; ++fn)
          acc[fm][fn] = __builtin_amdgcn_mfma_f32_16x16x32_bf16(
              af[fm], bfr[fn], acc[fm][fn], 0, 0, 0);
    }
    __builtin_amdgcn_s_barrier();
    if (kt + 2 < nk) stage(cur, (kt+2)*64);
  }
  const int crow = (lane >> 4) * 4;
  #pragma unroll
  for (int fm = 0; fm < 2; ++fm) {
    #pragma unroll
    for (int fn = 0; fn < 2; ++fn) {
      int col = n0 + wn + fn*16 + lrow;
      #pragma unroll
      for (int r = 0; r < 4; ++r) {
        int row = m0 + wm + fm*16 + crow + r;
        float v = acc[fm][fn][r] + bias[col];
        if (resid) v += resid[(size_t)row*N + col];
        outf[(size_t)row*N + col] = v;
      }
    }
  }
}

// ------- logits GEMM + fused partials; dbuf counted-vmcnt, XCD swizzle -------
__global__ __launch_bounds__(512) void k_logits(
    const __hip_bfloat16* __restrict__ A,   // h [2048][768] bf16
    const __hip_bfloat16* __restrict__ Bh,  // tokh [V][768] bf16 (or null)
    const float* __restrict__ Bf,           // tok [V][768] f32
    float* __restrict__ C,                  // logits [2048][V_] f32
    float2* __restrict__ part)              // [2048][NS2]
{
  __shared__ __align__(16) short lds_a[2][128*64];
  __shared__ __align__(16) short lds_b[2][128*64];
  const int t = threadIdx.x;
  const int bid = blockIdx.x;
  const int lid = (bid & 7) * (NS2*16/8) + (bid >> 3);   // bijective XCD swizzle
  const int m0 = (lid & 15) * 128;
  const int nt = lid >> 4;
  const int n0 = nt * 128;
  const int lane = t & 63;
  const int wid = t >> 6;
  const int wm = (wid >> 2) * 64;
  const int wn = (wid & 3) * 32;
  const int lrow = lane & 15;
  const int lkb = (lane >> 4) * 16;
  const int wbase = (t & 448) * 16;

  auto stageA = [&](int buf, int k0) {
    #pragma unroll
    for (int p = 0; p < 2; ++p) {
      int c = p*512 + t;
      int row = c >> 3;
      int colb = (c & 7) << 4;
      const char* src = (const char*)A + ((size_t)(m0+row)*768 + k0)*2 + (colb ^ ((row & 7) << 4));
      gl_lds16(src, (char*)lds_a[buf] + p*8192 + wbase);
    }
  };
  auto stageB = [&](int buf, int k0) {
    if (Bh) {
      #pragma unroll
      for (int p = 0; p < 2; ++p) {
        int c = p*512 + t;
        int row = c >> 3;
        int colb = (c & 7) << 4;
        const char* src = (const char*)Bh + ((size_t)(n0+row)*768 + k0)*2 + (colb ^ ((row & 7) << 4));
        gl_lds16(src, (char*)lds_b[buf] + p*8192 + wbase);
      }
    } else {
      #pragma unroll
      for (int p = 0; p < 2; ++p) {
        int c = p*512 + t;
        int row = c >> 3;
        int colb = (c & 7) << 4;
        int gn = n0 + row;
        s16x8 s = {0,0,0,0,0,0,0,0};
        if (gn < V_) {
          const char* src = (const char*)Bf + ((size_t)gn*768 + k0)*4 + colb*2;
          float4 v0 = *(const float4*)src;
          float4 v1 = *(const float4*)(src + 16);
          s[0]=f2bf(v0.x); s[1]=f2bf(v0.y); s[2]=f2bf(v0.z); s[3]=f2bf(v0.w);
          s[4]=f2bf(v1.x); s[5]=f2bf(v1.y); s[6]=f2bf(v1.z); s[7]=f2bf(v1.w);
        }
        int dst = (row*128 + colb) ^ ((row & 7) << 4);
        *(s16x8*)((char*)lds_b[buf] + dst) = s;
      }
    }
  };

  f32x4 acc[4][2];
  #pragma unroll
  for (int i = 0; i < 4; ++i)
    #pragma unroll
    for (int j = 0; j < 2; ++j)
      acc[i][j] = (f32x4){0.f, 0.f, 0.f, 0.f};

  stageA(0, 0); stageB(0, 0);
  stageA(1, 64); stageB(1, 64);
  const bool piped = (Bh != nullptr);
  for (int kt = 0; kt < 12; ++kt) {
    if (piped && kt + 1 < 12) asm volatile("s_waitcnt vmcnt(4)" ::: "memory");
    else                      asm volatile("s_waitcnt vmcnt(0) lgkmcnt(0)" ::: "memory");
    __builtin_amdgcn_s_barrier();
    const int cur = kt & 1;
    #pragma unroll
    for (int ks = 0; ks < 2; ++ks) {
      s16x8 af[4], bfr[2];
      #pragma unroll
      for (int f = 0; f < 4; ++f) {
        int row = wm + f*16 + lrow;
        int off = (row*128 + ks*64 + lkb) ^ ((row & 7) << 4);
        af[f] = *(const s16x8*)((const char*)lds_a[cur] + off);
      }
      #pragma unroll
      for (int f = 0; f < 2; ++f) {
        int row = wn + f*16 + lrow;
        int off = (row*128 + ks*64 + lkb) ^ ((row & 7) << 4);
        bfr[f] = *(const s16x8*)((const char*)lds_b[cur] + off);
      }
      #pragma unroll
      for (int fm = 0; fm < 4; ++fm)
        #pragma unroll
        for (int fn = 0; fn < 2; ++fn)
          acc[fm][fn] = __builtin_amdgcn_mfma_f32_16x16x32_bf16(
              af[fm], bfr[fn], acc[fm][fn], 0, 0, 0);
    }
    __builtin_amdgcn_s_barrier();
    if (kt + 2 < 12) { stageA(cur, (kt+2)*64); stageB(cur, (kt+2)*64); }
  }
  // ---- epilogue: plain-store C + per-row (max,sumexp) partials ----
  const int crow = (lane >> 4) * 4;
  bool valid[2];
  #pragma unroll
  for (int fn = 0; fn < 2; ++fn) valid[fn] = (n0 + wn + fn*16 + lrow) < V_;
  float2* red = (float2*)lds_a;
  #pragma unroll
  for (int fm = 0; fm < 4; ++fm) {
    #pragma unroll
    for (int r = 0; r < 4; ++r) {
      int rit = wm + fm*16 + crow + r;
      int row = m0 + rit;
      float m = -1e30f;
      #pragma unroll
      for (int fn = 0; fn < 2; ++fn) {
        if (valid[fn]) {
          float v = acc[fm][fn][r];
          C[(size_t)row*V_ + n0 + wn + fn*16 + lrow] = v;
          m = fmaxf(m, v);
        }
      }
      #pragma unroll
      for (int o = 1; o < 16; o <<= 1) m = fmaxf(m, __shfl_xor(m, o));
      float s = 0.f;
      #pragma unroll
      for (int fn = 0; fn < 2; ++fn)
        if (valid[fn]) s += __expf(acc[fm][fn][r] - m);
      #pragma unroll
      for (int o = 1; o < 16; o <<= 1) s += __shfl_xor(s, o);
      if (lrow == 0) red[rit*4 + (wid & 3)] = make_float2(m, s);
    }
  }
  __syncthreads();
  if (t < 128) {
    float M = -1e30f, S = 0.f;
    #pragma unroll
    for (int wc = 0; wc < 4; ++wc) {
      float2 p = red[t*4 + wc];
      float mn = fmaxf(M, p.x);
      S = S*__expf(M - mn) + p.y*__expf(p.x - mn);
      M = mn;
    }
    part[(size_t)(m0 + t)*NS2 + nt] = make_float2(M, S);
  }
}

// ------- combine per-tile partials -> per-row loss -------
__global__ void k_rowloss2(const float2* __restrict__ part,
                           const float* __restrict__ logits,
                           const int* __restrict__ tgt, float* __restrict__ rl) {
  int row = blockIdx.x;
  int lane = threadIdx.x;
  float M = -1e30f, S = 0.f;
  for (int i = lane; i < NS2; i += 64) {
    float2 p = part[(size_t)row*NS2 + i];
    float mn = fmaxf(M, p.x);
    S = S*__expf(M - mn) + p.y*__expf(p.x - mn);
    M = mn;
  }
  #pragma unroll
  for (int o = 1; o < 64; o <<= 1) {
    float Mo = __shfl_xor(M, o);
    float So = __shfl_xor(S, o);
    float mn = fmaxf(M, Mo);
    S = S*__expf(M - mn) + So*__expf(Mo - mn);
    M = mn;
  }
  if (lane == 0)
    rl[row] = (logf(S) + M) - logits[(size_t)row*V_ + tgt[row]];
}

// ------- flash attention: T14 async-split, K/V double-buffered -------
__global__ __launch_bounds__(256) void k_fattn(
    const __hip_bfloat16* __restrict__ qkv, const int* __restrict__ doc,
    __hip_bfloat16* __restrict__ y)
{
  __shared__ __align__(16) short q_lds[QBLK*64];       // 8 KB
  __shared__ __align__(16) short k_lds[2][KVB*64];     // 16 KB
  __shared__ __align__(16) short vt_lds[2][64*KVB];    // 16 KB
  __shared__ __align__(16) short p_lds[4][16*64];      // 8 KB
  __shared__ int doc_lds[T_];                          // 4 KB
  const int t = threadIdx.x;
  const int lane = t & 63;
  const int w = t >> 6;
  const int q0 = (gridDim.x - 1 - blockIdx.x) * QBLK;  // long blocks first
  const int h = blockIdx.y, b = blockIdx.z;
  const int lrow = lane & 15;
  const int lgrp = lane >> 4;
  const int crow = lgrp * 4;
  const int wbase = (t & 192) * 16;
  const short* qp = (const short*)qkv;

  auto stageK = [&](int kv0, int buf) {
    #pragma unroll
    for (int p = 0; p < 2; ++p) {
      int c = p*256 + t;
      int row = c >> 3;
      int colb = (c & 7) << 4;
      const char* src = (const char*)(qp + ((size_t)(b*T_ + kv0 + row))*QS3 + D_ + h*HD_)
                        + (colb ^ ((row & 7) << 4));
      gl_lds16(src, (char*)k_lds[buf] + p*4096 + wbase);
    }
  };

  // ---- prologue ----
  #pragma unroll
  for (int p = 0; p < 2; ++p) {
    int c = p*256 + t;
    int row = c >> 3;
    int colb = (c & 7) << 4;
    const char* src = (const char*)(qp + ((size_t)(b*T_ + q0 + row))*QS3 + h*HD_)
                      + (colb ^ ((row & 7) << 4));
    gl_lds16(src, (char*)q_lds + p*4096 + wbase);
  }
  #pragma unroll
  for (int i = 0; i < 4; ++i) doc_lds[t + i*256] = doc[b*T_ + t + i*256];
  stageK(0, 0);
  s16x8 vc0, vc1;
  {
    int c0 = t, c1 = 256 + t;
    vc0 = *(const s16x8*)(qp + ((size_t)(b*T_ + (c0>>3)))*QS3 + 2*D_ + h*HD_ + (c0&7)*8);
    vc1 = *(const s16x8*)(qp + ((size_t)(b*T_ + (c1>>3)))*QS3 + 2*D_ + h*HD_ + (c1&7)*8);
  }
  __syncthreads();   // Q, doc, K[0] in LDS; V[0] in regs (prologue full drain)

  int docq[4];
  #pragma unroll
  for (int r = 0; r < 4; ++r)
    docq[r] = doc_lds[q0 + w*16 + crow + r];

  float m_r[4], l_r[4];
  #pragma unroll
  for (int r = 0; r < 4; ++r) { m_r[r] = -1e30f; l_r[r] = 0.f; }
  f32x4 o[4];
  #pragma unroll
  for (int fd = 0; fd < 4; ++fd) o[fd] = (f32x4){0.f,0.f,0.f,0.f};

  const int ntiles = q0/KVB + 1;
  for (int kt = 0; kt < ntiles; ++kt) {
    const int kv0 = kt * KVB;
    const int cur = kt & 1;
    const bool hn = (kt + 1 < ntiles);
    // ---- issue next tile's K (gl_lds) + V (reg loads) ----
    s16x8 vn0, vn1;
    if (hn) {
      stageK(kv0 + KVB, cur ^ 1);
      int c0 = t, c1 = 256 + t;
      vn0 = *(const s16x8*)(qp + ((size_t)(b*T_ + kv0 + KVB + (c0>>3)))*QS3 + 2*D_ + h*HD_ + (c0&7)*8);
      vn1 = *(const s16x8*)(qp + ((size_t)(b*T_ + kv0 + KVB + (c1>>3)))*QS3 + 2*D_ + h*HD_ + (c1&7)*8);
    }
    // ---- scatter current V regs into vt_lds[cur] (compiler waits vc deps) ----
    {
      int c0 = t, kvr0 = c0 >> 3, d00 = (c0 & 7)*8;
      #pragma unroll
      for (int j = 0; j < 8; ++j) {
        int d = d00 + j;
        int off = (d*128 + kvr0*2) ^ ((d & 7) << 4);
        *(short*)((char*)vt_lds[cur] + off) = vc0[j];
      }
      int c1 = 256 + t, kvr1 = c1 >> 3, d01 = (c1 & 7)*8;
      #pragma unroll
      for (int j = 0; j < 8; ++j) {
        int d = d01 + j;
        int off = (d*128 + kvr1*2) ^ ((d & 7) << 4);
        *(short*)((char*)vt_lds[cur] + off) = vc1[j];
      }
    }
    // K[kt] landed (only next tile's 2 gl_lds + 2 V loads may remain in flight)
    if (hn) asm volatile("s_waitcnt vmcnt(4)" ::: "memory");
    else    asm volatile("s_waitcnt vmcnt(0)" ::: "memory");
    __builtin_amdgcn_s_barrier();

    f32x4 sfr[4];
    #pragma unroll
    for (int fn = 0; fn < 4; ++fn) sfr[fn] = (f32x4){0.f,0.f,0.f,0.f};
    #pragma unroll
    for (int ks = 0; ks < 2; ++ks) {
      int arow = w*16 + lrow;
      s16x8 af = *(const s16x8*)((const char*)q_lds +
                 ((arow*128 + lgrp*16 + ks*64) ^ ((arow & 7) << 4)));
      #pragma unroll
      for (int fn = 0; fn < 4; ++fn) {
        int brow = fn*16 + lrow;
        s16x8 bf = *(const s16x8*)((const char*)k_lds[cur] +
                   ((brow*128 + lgrp*16 + ks*64) ^ ((brow & 7) << 4)));
        sfr[fn] = __builtin_amdgcn_mfma_f32_16x16x32_bf16(af, bf, sfr[fn], 0, 0, 0);
      }
    }
    int dk[4];
    #pragma unroll
    for (int fn = 0; fn < 4; ++fn) dk[fn] = doc_lds[kv0 + fn*16 + lrow];
    float rowmax[4] = {-1e30f, -1e30f, -1e30f, -1e30f};
    #pragma unroll
    for (int fn = 0; fn < 4; ++fn) {
      int col = kv0 + fn*16 + lrow;
      #pragma unroll
      for (int r = 0; r < 4; ++r) {
        int qrow = q0 + w*16 + crow + r;
        bool ok = (col <= qrow) && (dk[fn] == docq[r]);
        float v = ok ? sfr[fn][r] * 0.125f : -1e30f;
        sfr[fn][r] = v;
        rowmax[r] = fmaxf(rowmax[r], v);
      }
    }
    #pragma unroll
    for (int r = 0; r < 4; ++r) {
      float v = rowmax[r];
      #pragma unroll
      for (int off = 1; off < 16; off <<= 1) v = fmaxf(v, __shfl_xor(v, off));
      rowmax[r] = v;
    }
    float alpha[4], psum[4];
    #pragma unroll
    for (int r = 0; r < 4; ++r) {
      float mn = fmaxf(m_r[r], rowmax[r]);
      alpha[r] = __expf(m_r[r] - mn);
      m_r[r] = mn;
      psum[r] = 0.f;
    }
    #pragma unroll
    for (int fn = 0; fn < 4; ++fn) {
      #pragma unroll
      for (int r = 0; r < 4; ++r) {
        float sv = sfr[fn][r];
        float p = (sv < -5e29f) ? 0.f : __expf(sv - m_r[r]);
        psum[r] += p;
        int rl_ = crow + r;
        int off = (rl_*128 + (fn*16 + lrow)*2) ^ ((rl_ & 7) << 4);
        *(short*)((char*)p_lds[w] + off) = f2bf(p);
      }
    }
    #pragma unroll
    for (int r = 0; r < 4; ++r) {
      float v = psum[r];
      #pragma unroll
      for (int off = 1; off < 16; off <<= 1) v += __shfl_xor(v, off);
      l_r[r] = l_r[r]*alpha[r] + v;
    }
    #pragma unroll
    for (int fd = 0; fd < 4; ++fd)
      #pragma unroll
      for (int r = 0; r < 4; ++r)
        o[fd][r] *= alpha[r];
    // p_lds[w] is wave-private; vt_lds[cur]/k_lds[cur] protected by the barrier above.
    #pragma unroll
    for (int ks = 0; ks < 2; ++ks) {
      s16x8 af = *(const s16x8*)((const char*)p_lds[w] +
                 ((lrow*128 + lgrp*16 + ks*64) ^ ((lrow & 7) << 4)));
      #pragma unroll
      for (int fd = 0; fd < 4; ++fd) {
        int brow = fd*16 + lrow;
        s16x8 bf = *(const s16x8*)((const char*)vt_lds[cur] +
                   ((brow*128 + lgrp*16 + ks*64) ^ ((brow & 7) << 4)));
        o[fd] = __builtin_amdgcn_mfma_f32_16x16x32_bf16(af, bf, o[fd], 0, 0, 0);
      }
    }
    __builtin_amdgcn_s_barrier();   // all waves done reading [cur] before next overwrite
    vc0 = vn0; vc1 = vn1;
  }
  #pragma unroll
  for (int r = 0; r < 4; ++r) {
    float inv = 1.f / l_r[r];
    int rowg = b*T_ + q0 + w*16 + crow + r;
    #pragma unroll
    for (int fd = 0; fd < 4; ++fd) {
      int col = h*HD_ + fd*16 + lrow;
      y[(size_t)rowg*D_ + col] = __float2bfloat16(o[fd][r] * inv);
    }
  }
}

// ---------------- fallback per-row log-softmax ----------------
__global__ void k_rowloss(const float* __restrict__ logits,
                          const int* __restrict__ tgt, float* __restrict__ rl) {
  __shared__ float red[4];
  int row = blockIdx.x;
  const float* lr = logits + (size_t)row * V_;
  int tid = threadIdx.x;
  float m = -1e30f;
  for (int v = tid; v < V_; v += 256) m = fmaxf(m, lr[v]);
  #pragma unroll
  for (int o = 1; o < 64; o <<= 1) m = fmaxf(m, __shfl_xor(m, o));
  if ((tid & 63) == 0) red[tid >> 6] = m;
  __syncthreads();
  m = fmaxf(fmaxf(red[0], red[1]), fmaxf(red[2], red[3]));
  __syncthreads();
  float s = 0.f;
  for (int v = tid; v < V_; v += 256) s += __expf(lr[v] - m);
  #pragma unroll
  for (int o = 1; o < 64; o <<= 1) s += __shfl_xor(s, o);
  if ((tid & 63) == 0) red[tid >> 6] = s;
  __syncthreads();
  if (tid == 0) {
    s = red[0]+red[1]+red[2]+red[3];
    rl[row] = (logf(s) + m) - lr[tgt[row]];
  }
}

// ---------------- final loss = mean(rl) ----------------
__global__ void k_loss(const float* __restrict__ rl, float* __restrict__ out) {
  __shared__ float red[4];
  int tid = threadIdx.x;
  float s = 0.f;
  for (int i = tid; i < NTOK; i += 256) s += rl[i];
  #pragma unroll
  for (int o = 1; o < 64; o <<= 1) s += __shfl_xor(s, o);
  if ((tid & 63) == 0) red[tid >> 6] = s;
  __syncthreads();
  if (tid == 0) {
    s = red[0]+red[1]+red[2]+red[3];
    out[0] = s / (float)NTOK;
  }
}

extern "C" void kernel_launch(void* const* d_in, const int* in_sizes, int n_in,
                              void* d_out, int out_size, void* d_ws, size_t ws_size,
                              hipStream_t stream) {
  const int*   idx   = (const int*)d_in[0];
  const int*   tgt   = (const int*)d_in[1];
  const float* tok   = (const float*)d_in[2];
  const float* pos   = (const float*)d_in[3];
  const float* ln1_g = (const float*)d_in[4];
  const float* ln1_b = (const float*)d_in[5];
  const float* ln2_g = (const float*)d_in[6];
  const float* ln2_b = (const float*)d_in[7];
  const float* W_qkv = (const float*)d_in[8];
  const float* b_qkv = (const float*)d_in[9];
  const float* W_proj= (const float*)d_in[10];
  const float* b_proj= (const float*)d_in[11];
  const float* W_fc1 = (const float*)d_in[12];
  const float* b_fc1 = (const float*)d_in[13];
  const float* W_fc2 = (const float*)d_in[14];
  const float* b_fc2 = (const float*)d_in[15];
  const float* lnf_g = (const float*)d_in[16];
  const float* lnf_b = (const float*)d_in[17];

  float* out = (float*)d_out;

  char* ob = (char*)d_out;
  float*           x    = (float*)(ob + 0);
  __hip_bfloat16*  qkv  = (__hip_bfloat16*)(ob + (size_t)6291456);
  __hip_bfloat16*  y    = (__hip_bfloat16*)(ob + (size_t)15728640);
  __hip_bfloat16*  tff  = (__hip_bfloat16*)(ob + (size_t)18874368);
  __hip_bfloat16*  WTq  = (__hip_bfloat16*)(ob + (size_t)40894464);
  __hip_bfloat16*  WTp  = (__hip_bfloat16*)(ob + (size_t)62128128);
  __hip_bfloat16*  WT1  = (__hip_bfloat16*)(ob + (size_t)69206016);
  __hip_bfloat16*  WT2  = (__hip_bfloat16*)(ob + (size_t)97517568);  // ends 125,829,120

  char* wb = (char*)d_ws;
  __hip_bfloat16* h    = (__hip_bfloat16*)(wb + 0);
  int*    doc  = (int*)  (wb + (size_t)3145728);
  float*  rl   = (float*)(wb + (size_t)3153920);
  float2* part = (float2*)(wb + (size_t)3162112);
  __hip_bfloat16* tokh = (__hip_bfloat16*)(wb + (size_t)9601024);
  const size_t ws_need_part = (size_t)9601024;
  const size_t ws_need_tokh = (size_t)9601024 + 77194752 + 131072;
  const bool fused_loss = (ws_size >= ws_need_part);
  const bool use_tokh   = (ws_size >= ws_need_tokh);

  dim3 tb(32, 8);
  k_wt<<<dim3(2304/32, 768/32, L_), tb, 0, stream>>>(W_qkv,  WTq,  768, 2304);
  k_wt<<<dim3( 768/32, 768/32, L_), tb, 0, stream>>>(W_proj, WTp,  768,  768);
  k_wt<<<dim3(3072/32, 768/32, L_), tb, 0, stream>>>(W_fc1,  WT1,  768, 3072);
  k_wt<<<dim3( 768/32,3072/32, L_), tb, 0, stream>>>(W_fc2,  WT2, 3072,  768);
  if (use_tokh)
    k_cast_tok<<<2048, 256, 0, stream>>>(tok, tokh, (long)V_*768/8);

  k_embed<<<(NTOK*D_ + 255)/256, 256, 0, stream>>>(idx, tok, pos, x);
  k_docid<<<1, 64, 0, stream>>>(idx, doc);

  for (int l = 0; l < L_; ++l) {
    k_ln<<<NTOK, 64, 0, stream>>>(x, ln1_g + l*D_, ln1_b + l*D_, h);
    k_mfma_nt<<<dim3(2304/128, NTOK/128), 512, 0, stream>>>(
        h, WTq + (size_t)l*2304*768, nullptr, b_qkv + (size_t)l*2304, nullptr,
        nullptr, qkv, NTOK, 2304, 768, 0);
    k_fattn<<<dim3(T_/QBLK, H_, B_), 256, 0, stream>>>(qkv, doc, y);
    k_mfma_nt64<<<dim3(768/64, NTOK/64), 256, 0, stream>>>(
        y, WTp + (size_t)l*768*768, b_proj + (size_t)l*768, x, x,
        NTOK, 768, 768);
    k_ln<<<NTOK, 64, 0, stream>>>(x, ln2_g + l*D_, ln2_b + l*D_, h);
    k_mfma_nt<<<dim3(3072/128, NTOK/128), 512, 0, stream>>>(
        h, WT1 + (size_t)l*3072*768, nullptr, b_fc1 + (size_t)l*3072, nullptr,
        nullptr, tff, NTOK, 3072, 768, 1);
    k_mfma_nt64<<<dim3(768/64, NTOK/64), 256, 0, stream>>>(
        tff, WT2 + (size_t)l*768*3072, b_fc2 + (size_t)l*768, x, x,
        NTOK, 768, 3072);
  }
  k_ln<<<NTOK, 64, 0, stream>>>(x, lnf_g, lnf_b, h);

  if (fused_loss) {
    k_logits<<<NS2*16, 512, 0, stream>>>(
        h, use_tokh ? tokh : nullptr, tok, out, part);
    k_rowloss2<<<NTOK, 64, 0, stream>>>(part, out, tgt, rl);
  } else {
    k_mfma_nt<<<dim3((V_ + 127)/128, NTOK/128), 512, 0, stream>>>(
        h, nullptr, tok, nullptr, nullptr, out, nullptr, NTOK, V_, 768, 0);
    k_rowloss<<<NTOK, 256, 0, stream>>>(out, tgt, rl);
  }
  k_loss<<<1, 256, 0, stream>>>(rl, out + (size_t)NTOK*V_);
}

// Round 20
// 1484.934 us; speedup vs baseline: 1.0099x; 1.0099x over previous
//
#include <hip/hip_runtime.h>
#include <hip/hip_bf16.h>
#include <math.h>

#define V_ 50257
#define L_ 6
#define H_ 12
#define D_ 768
#define HD_ 64
#define FF_ 3072
#define B_ 2
#define T_ 1024
#define NTOK (B_*T_)
#define EOS_ 50256
#define QBLK 64
#define KVB 64
#define NS2 393            // number of 128-col logit tiles
#define QS3 (3*D_)         // qkv row stride in elements

typedef __attribute__((ext_vector_type(8))) short s16x8;
typedef __attribute__((ext_vector_type(4))) float f32x4;

__device__ __forceinline__ short f2bf(float f) {
  __hip_bfloat16 h = __float2bfloat16(f);
  return *reinterpret_cast<short*>(&h);
}

// async global->LDS, 16B per lane; l must be the WAVE-uniform base (HW adds lane*16)
__device__ __forceinline__ void gl_lds16(const void* g, void* l) {
  __builtin_amdgcn_global_load_lds(
      (const __attribute__((address_space(1))) unsigned int*)g,
      (__attribute__((address_space(3))) unsigned int*)l, 16, 0, 0);
}

// ---------------- embedding ----------------
__global__ void k_embed(const int* __restrict__ idx, const float* __restrict__ tok,
                        const float* __restrict__ pos, float* __restrict__ x) {
  int gid = blockIdx.x * blockDim.x + threadIdx.x;
  const int total = NTOK * D_;
  if (gid >= total) return;
  int row = gid / D_;
  int d = gid - row * D_;
  int t = row & (T_ - 1);
  x[gid] = tok[(size_t)idx[row] * D_ + d] + pos[t * D_ + d];
}

// ---------------- doc ids ----------------
__global__ void k_docid(const int* __restrict__ idx, int* __restrict__ doc) {
  int b = threadIdx.x;
  if (b >= B_) return;
  int c = 0;
  for (int t = 0; t < T_; ++t) {
    int e = (idx[b*T_ + t] == EOS_) ? 1 : 0;
    doc[b*T_ + t] = c;
    c += e;
  }
}

// ---------------- tok f32 -> bf16 cast --------
__global__ void k_cast_tok(const float* __restrict__ in,
                           __hip_bfloat16* __restrict__ out, long n8) {
  long i = (long)blockIdx.x*blockDim.x + threadIdx.x;
  long stride = (long)gridDim.x*blockDim.x;
  for (; i < n8; i += stride) {
    const float4* src = (const float4*)(in + i*8);
    float4 v0 = src[0], v1 = src[1];
    s16x8 s;
    s[0]=f2bf(v0.x); s[1]=f2bf(v0.y); s[2]=f2bf(v0.z); s[3]=f2bf(v0.w);
    s[4]=f2bf(v1.x); s[5]=f2bf(v1.y); s[6]=f2bf(v1.z); s[7]=f2bf(v1.w);
    *(s16x8*)((short*)out + i*8) = s;
  }
}

// ---------------- layernorm ----------------
__global__ void k_ln(const float* __restrict__ x, const float* __restrict__ g,
                     const float* __restrict__ b, __hip_bfloat16* __restrict__ out) {
  int row = blockIdx.x;
  const float* xr = x + (size_t)row * D_;
  int lane = threadIdx.x;
  float vals[D_/64];
  float s = 0.f;
  #pragma unroll
  for (int i = 0; i < D_/64; ++i) { vals[i] = xr[lane + i*64]; s += vals[i]; }
  #pragma unroll
  for (int o = 1; o < 64; o <<= 1) s += __shfl_xor(s, o);
  float mu = s * (1.f/D_);
  float v = 0.f;
  #pragma unroll
  for (int i = 0; i < D_/64; ++i) { float d0 = vals[i]-mu; v += d0*d0; }
  #pragma unroll
  for (int o = 1; o < 64; o <<= 1) v += __shfl_xor(v, o);
  float inv = rsqrtf(v * (1.f/D_) + 1e-5f);
  #pragma unroll
  for (int i = 0; i < D_/64; ++i) {
    int d = lane + i*64;
    out[(size_t)row*D_ + d] = __float2bfloat16((vals[i]-mu)*inv*g[d] + b[d]);
  }
}

// ------- weight transpose+cast -------
__global__ void k_wt(const float* __restrict__ in, __hip_bfloat16* __restrict__ out,
                     int K, int N) {
  __shared__ float tile[32][33];
  int l = blockIdx.z;
  const float* src = in + (size_t)l*K*N;
  __hip_bfloat16* dst = out + (size_t)l*N*K;
  int n0 = blockIdx.x*32, k0 = blockIdx.y*32;
  int tx = threadIdx.x, ty = threadIdx.y;
  #pragma unroll
  for (int i = 0; i < 4; ++i)
    tile[ty + i*8][tx] = src[(size_t)(k0 + ty + i*8)*N + n0 + tx];
  __syncthreads();
  #pragma unroll
  for (int i = 0; i < 4; ++i)
    dst[(size_t)(n0 + ty + i*8)*K + k0 + tx] = __float2bfloat16(tile[tx][ty + i*8]);
}

// ------- MFMA NT GEMM (128x64x64), 256 thr, 4 waves 2x2, dbuf counted-vmcnt -------
// BN=64 doubles grid size (qkv 288->576, fc1 384->768 blocks) for CU coverage.
__global__ __launch_bounds__(256) void k_mfma_nt(
    const __hip_bfloat16* __restrict__ A,
    const __hip_bfloat16* __restrict__ Bh,
    const float* __restrict__ Bf,
    const float* __restrict__ bias,
    const float* resid,
    float* outf, __hip_bfloat16* outh,
    int M, int N, int K, int gelu)
{
  __shared__ __align__(16) short lds_a[2][128*64];   // 32 KB
  __shared__ __align__(16) short lds_b[2][64*64];    // 16 KB
  const int t = threadIdx.x;
  const int m0 = blockIdx.y * 128;
  const int n0 = blockIdx.x * 64;
  const int lane = t & 63;
  const int wid = t >> 6;
  const int wm = (wid >> 1) * 64;    // 0/64
  const int wn = (wid & 1) * 32;     // 0/32
  const int lrow = lane & 15;
  const int lkb = (lane >> 4) * 16;
  const int wbase = (t & 192) * 16;

  auto stageA = [&](int buf, int k0) {
    #pragma unroll
    for (int p = 0; p < 4; ++p) {
      int c = p*256 + t;
      int row = c >> 3;
      int colb = (c & 7) << 4;
      const char* src = (const char*)A + ((size_t)(m0+row)*K + k0)*2 + (colb ^ ((row & 7) << 4));
      gl_lds16(src, (char*)lds_a[buf] + p*4096 + wbase);
    }
  };
  auto stageB = [&](int buf, int k0) {
    if (Bh) {
      #pragma unroll
      for (int p = 0; p < 2; ++p) {
        int c = p*256 + t;
        int row = c >> 3;
        int colb = (c & 7) << 4;
        const char* src = (const char*)Bh + ((size_t)(n0+row)*K + k0)*2 + (colb ^ ((row & 7) << 4));
        gl_lds16(src, (char*)lds_b[buf] + p*4096 + wbase);
      }
    } else {
      #pragma unroll
      for (int p = 0; p < 2; ++p) {
        int c = p*256 + t;
        int row = c >> 3;
        int colb = (c & 7) << 4;
        int gn = n0 + row;
        s16x8 s = {0,0,0,0,0,0,0,0};
        if (gn < N) {
          const char* src = (const char*)Bf + ((size_t)gn*K + k0)*4 + colb*2;
          float4 v0 = *(const float4*)src;
          float4 v1 = *(const float4*)(src + 16);
          s[0]=f2bf(v0.x); s[1]=f2bf(v0.y); s[2]=f2bf(v0.z); s[3]=f2bf(v0.w);
          s[4]=f2bf(v1.x); s[5]=f2bf(v1.y); s[6]=f2bf(v1.z); s[7]=f2bf(v1.w);
        }
        int dst = (row*128 + colb) ^ ((row & 7) << 4);
        *(s16x8*)((char*)lds_b[buf] + dst) = s;
      }
    }
  };

  f32x4 acc[4][2];
  #pragma unroll
  for (int i = 0; i < 4; ++i)
    #pragma unroll
    for (int j = 0; j < 2; ++j)
      acc[i][j] = (f32x4){0.f, 0.f, 0.f, 0.f};

  const int nk = K >> 6;
  stageA(0, 0); stageB(0, 0);
  stageA(1, 64); stageB(1, 64);
  const bool piped = (Bh != nullptr);
  for (int kt = 0; kt < nk; ++kt) {
    // 6 loads/thread/tile -> tile kt landed when next tile's 6 remain in flight
    if (piped && kt + 1 < nk) asm volatile("s_waitcnt vmcnt(6)" ::: "memory");
    else                      asm volatile("s_waitcnt vmcnt(0) lgkmcnt(0)" ::: "memory");
    __builtin_amdgcn_s_barrier();
    const int cur = kt & 1;
    #pragma unroll
    for (int ks = 0; ks < 2; ++ks) {
      s16x8 af[4], bfr[2];
      #pragma unroll
      for (int f = 0; f < 4; ++f) {
        int row = wm + f*16 + lrow;
        int off = (row*128 + ks*64 + lkb) ^ ((row & 7) << 4);
        af[f] = *(const s16x8*)((const char*)lds_a[cur] + off);
      }
      #pragma unroll
      for (int f = 0; f < 2; ++f) {
        int row = wn + f*16 + lrow;
        int off = (row*128 + ks*64 + lkb) ^ ((row & 7) << 4);
        bfr[f] = *(const s16x8*)((const char*)lds_b[cur] + off);
      }
      #pragma unroll
      for (int fm = 0; fm < 4; ++fm)
        #pragma unroll
        for (int fn = 0; fn < 2; ++fn)
          acc[fm][fn] = __builtin_amdgcn_mfma_f32_16x16x32_bf16(
              af[fm], bfr[fn], acc[fm][fn], 0, 0, 0);
    }
    __builtin_amdgcn_s_barrier();
    if (kt + 2 < nk) { stageA(cur, (kt+2)*64); stageB(cur, (kt+2)*64); }
  }
  const int crow = (lane >> 4) * 4;
  #pragma unroll
  for (int fm = 0; fm < 4; ++fm) {
    #pragma unroll
    for (int fn = 0; fn < 2; ++fn) {
      int col = n0 + wn + fn*16 + lrow;
      if (col >= N) continue;
      #pragma unroll
      for (int r = 0; r < 4; ++r) {
        int row = m0 + wm + fm*16 + crow + r;
        float v = acc[fm][fn][r];
        if (bias) v += bias[col];
        if (gelu) v = 0.5f * v * (1.f + erff(v * 0.70710678118654752f));
        if (resid) v += resid[(size_t)row*N + col];
        if (outf) outf[(size_t)row*N + col] = v;
        else      outh[(size_t)row*N + col] = __float2bfloat16(v);
      }
    }
  }
}

// ------- small-N MFMA NT GEMM (64x64x64): proj, fc2 — dbuf counted-vmcnt -------
__global__ __launch_bounds__(256) void k_mfma_nt64(
    const __hip_bfloat16* __restrict__ A,
    const __hip_bfloat16* __restrict__ Bh,
    const float* __restrict__ bias,
    const float* resid,
    float* outf,
    int M, int N, int K)
{
  __shared__ __align__(16) short lds_a[2][64*64];
  __shared__ __align__(16) short lds_b[2][64*64];
  const int t = threadIdx.x;
  const int m0 = blockIdx.y * 64;
  const int n0 = blockIdx.x * 64;
  const int lane = t & 63;
  const int wid = t >> 6;
  const int wm = (wid >> 1) * 32;
  const int wn = (wid & 1) * 32;
  const int lrow = lane & 15;
  const int lkb = (lane >> 4) * 16;
  const int wbase = (t & 192) * 16;

  auto stage = [&](int buf, int k0) {
    #pragma unroll
    for (int p = 0; p < 2; ++p) {
      int c = p*256 + t;
      int row = c >> 3;
      int colb = (c & 7) << 4;
      const char* srcA = (const char*)A + ((size_t)(m0+row)*K + k0)*2 + (colb ^ ((row & 7) << 4));
      gl_lds16(srcA, (char*)lds_a[buf] + p*4096 + wbase);
    }
    #pragma unroll
    for (int p = 0; p < 2; ++p) {
      int c = p*256 + t;
      int row = c >> 3;
      int colb = (c & 7) << 4;
      const char* srcB = (const char*)Bh + ((size_t)(n0+row)*K + k0)*2 + (colb ^ ((row & 7) << 4));
      gl_lds16(srcB, (char*)lds_b[buf] + p*4096 + wbase);
    }
  };

  f32x4 acc[2][2];
  #pragma unroll
  for (int i = 0; i < 2; ++i)
    #pragma unroll
    for (int j = 0; j < 2; ++j)
      acc[i][j] = (f32x4){0.f, 0.f, 0.f, 0.f};

  const int nk = K >> 6;
  stage(0, 0);
  stage(1, 64);
  for (int kt = 0; kt < nk; ++kt) {
    if (kt + 1 < nk) asm volatile("s_waitcnt vmcnt(4)" ::: "memory");
    else             asm volatile("s_waitcnt vmcnt(0)" ::: "memory");
    __builtin_amdgcn_s_barrier();
    const int cur = kt & 1;
    #pragma unroll
    for (int ks = 0; ks < 2; ++ks) {
      s16x8 af[2], bfr[2];
      #pragma unroll
      for (int f = 0; f < 2; ++f) {
        int row = wm + f*16 + lrow;
        int off = (row*128 + ks*64 + lkb) ^ ((row & 7) << 4);
        af[f] = *(const s16x8*)((const char*)lds_a[cur] + off);
      }
      #pragma unroll
      for (int f = 0; f < 2; ++f) {
        int row = wn + f*16 + lrow;
        int off = (row*128 + ks*64 + lkb) ^ ((row & 7) << 4);
        bfr[f] = *(const s16x8*)((const char*)lds_b[cur] + off);
      }
      #pragma unroll
      for (int fm = 0; fm < 2; ++fm)
        #pragma unroll
        for (int fn = 0; fn < 2; ++fn)
          acc[fm][fn] = __builtin_amdgcn_mfma_f32_16x16x32_bf16(
              af[fm], bfr[fn], acc[fm][fn], 0, 0, 0);
    }
    __builtin_amdgcn_s_barrier();
    if (kt + 2 < nk) stage(cur, (kt+2)*64);
  }
  const int crow = (lane >> 4) * 4;
  #pragma unroll
  for (int fm = 0; fm < 2; ++fm) {
    #pragma unroll
    for (int fn = 0; fn < 2; ++fn) {
      int col = n0 + wn + fn*16 + lrow;
      #pragma unroll
      for (int r = 0; r < 4; ++r) {
        int row = m0 + wm + fm*16 + crow + r;
        float v = acc[fm][fn][r] + bias[col];
        if (resid) v += resid[(size_t)row*N + col];
        outf[(size_t)row*N + col] = v;
      }
    }
  }
}

// ------- logits GEMM + fused partials; dbuf counted-vmcnt, XCD swizzle -------
__global__ __launch_bounds__(512) void k_logits(
    const __hip_bfloat16* __restrict__ A,   // h [2048][768] bf16
    const __hip_bfloat16* __restrict__ Bh,  // tokh [V][768] bf16 (or null)
    const float* __restrict__ Bf,           // tok [V][768] f32
    float* __restrict__ C,                  // logits [2048][V_] f32
    float2* __restrict__ part)              // [2048][NS2]
{
  __shared__ __align__(16) short lds_a[2][128*64];
  __shared__ __align__(16) short lds_b[2][128*64];
  const int t = threadIdx.x;
  const int bid = blockIdx.x;
  const int lid = (bid & 7) * (NS2*16/8) + (bid >> 3);   // bijective XCD swizzle
  const int m0 = (lid & 15) * 128;
  const int nt = lid >> 4;
  const int n0 = nt * 128;
  const int lane = t & 63;
  const int wid = t >> 6;
  const int wm = (wid >> 2) * 64;
  const int wn = (wid & 3) * 32;
  const int lrow = lane & 15;
  const int lkb = (lane >> 4) * 16;
  const int wbase = (t & 448) * 16;

  auto stageA = [&](int buf, int k0) {
    #pragma unroll
    for (int p = 0; p < 2; ++p) {
      int c = p*512 + t;
      int row = c >> 3;
      int colb = (c & 7) << 4;
      const char* src = (const char*)A + ((size_t)(m0+row)*768 + k0)*2 + (colb ^ ((row & 7) << 4));
      gl_lds16(src, (char*)lds_a[buf] + p*8192 + wbase);
    }
  };
  auto stageB = [&](int buf, int k0) {
    if (Bh) {
      #pragma unroll
      for (int p = 0; p < 2; ++p) {
        int c = p*512 + t;
        int row = c >> 3;
        int colb = (c & 7) << 4;
        const char* src = (const char*)Bh + ((size_t)(n0+row)*768 + k0)*2 + (colb ^ ((row & 7) << 4));
        gl_lds16(src, (char*)lds_b[buf] + p*8192 + wbase);
      }
    } else {
      #pragma unroll
      for (int p = 0; p < 2; ++p) {
        int c = p*512 + t;
        int row = c >> 3;
        int colb = (c & 7) << 4;
        int gn = n0 + row;
        s16x8 s = {0,0,0,0,0,0,0,0};
        if (gn < V_) {
          const char* src = (const char*)Bf + ((size_t)gn*768 + k0)*4 + colb*2;
          float4 v0 = *(const float4*)src;
          float4 v1 = *(const float4*)(src + 16);
          s[0]=f2bf(v0.x); s[1]=f2bf(v0.y); s[2]=f2bf(v0.z); s[3]=f2bf(v0.w);
          s[4]=f2bf(v1.x); s[5]=f2bf(v1.y); s[6]=f2bf(v1.z); s[7]=f2bf(v1.w);
        }
        int dst = (row*128 + colb) ^ ((row & 7) << 4);
        *(s16x8*)((char*)lds_b[buf] + dst) = s;
      }
    }
  };

  f32x4 acc[4][2];
  #pragma unroll
  for (int i = 0; i < 4; ++i)
    #pragma unroll
    for (int j = 0; j < 2; ++j)
      acc[i][j] = (f32x4){0.f, 0.f, 0.f, 0.f};

  stageA(0, 0); stageB(0, 0);
  stageA(1, 64); stageB(1, 64);
  const bool piped = (Bh != nullptr);
  for (int kt = 0; kt < 12; ++kt) {
    if (piped && kt + 1 < 12) asm volatile("s_waitcnt vmcnt(4)" ::: "memory");
    else                      asm volatile("s_waitcnt vmcnt(0) lgkmcnt(0)" ::: "memory");
    __builtin_amdgcn_s_barrier();
    const int cur = kt & 1;
    #pragma unroll
    for (int ks = 0; ks < 2; ++ks) {
      s16x8 af[4], bfr[2];
      #pragma unroll
      for (int f = 0; f < 4; ++f) {
        int row = wm + f*16 + lrow;
        int off = (row*128 + ks*64 + lkb) ^ ((row & 7) << 4);
        af[f] = *(const s16x8*)((const char*)lds_a[cur] + off);
      }
      #pragma unroll
      for (int f = 0; f < 2; ++f) {
        int row = wn + f*16 + lrow;
        int off = (row*128 + ks*64 + lkb) ^ ((row & 7) << 4);
        bfr[f] = *(const s16x8*)((const char*)lds_b[cur] + off);
      }
      #pragma unroll
      for (int fm = 0; fm < 4; ++fm)
        #pragma unroll
        for (int fn = 0; fn < 2; ++fn)
          acc[fm][fn] = __builtin_amdgcn_mfma_f32_16x16x32_bf16(
              af[fm], bfr[fn], acc[fm][fn], 0, 0, 0);
    }
    __builtin_amdgcn_s_barrier();
    if (kt + 2 < 12) { stageA(cur, (kt+2)*64); stageB(cur, (kt+2)*64); }
  }
  // ---- epilogue: plain-store C + per-row (max,sumexp) partials ----
  const int crow = (lane >> 4) * 4;
  bool valid[2];
  #pragma unroll
  for (int fn = 0; fn < 2; ++fn) valid[fn] = (n0 + wn + fn*16 + lrow) < V_;
  float2* red = (float2*)lds_a;
  #pragma unroll
  for (int fm = 0; fm < 4; ++fm) {
    #pragma unroll
    for (int r = 0; r < 4; ++r) {
      int rit = wm + fm*16 + crow + r;
      int row = m0 + rit;
      float m = -1e30f;
      #pragma unroll
      for (int fn = 0; fn < 2; ++fn) {
        if (valid[fn]) {
          float v = acc[fm][fn][r];
          C[(size_t)row*V_ + n0 + wn + fn*16 + lrow] = v;
          m = fmaxf(m, v);
        }
      }
      #pragma unroll
      for (int o = 1; o < 16; o <<= 1) m = fmaxf(m, __shfl_xor(m, o));
      float s = 0.f;
      #pragma unroll
      for (int fn = 0; fn < 2; ++fn)
        if (valid[fn]) s += __expf(acc[fm][fn][r] - m);
      #pragma unroll
      for (int o = 1; o < 16; o <<= 1) s += __shfl_xor(s, o);
      if (lrow == 0) red[rit*4 + (wid & 3)] = make_float2(m, s);
    }
  }
  __syncthreads();
  if (t < 128) {
    float M = -1e30f, S = 0.f;
    #pragma unroll
    for (int wc = 0; wc < 4; ++wc) {
      float2 p = red[t*4 + wc];
      float mn = fmaxf(M, p.x);
      S = S*__expf(M - mn) + p.y*__expf(p.x - mn);
      M = mn;
    }
    part[(size_t)(m0 + t)*NS2 + nt] = make_float2(M, S);
  }
}

// ------- combine per-tile partials -> per-row loss -------
__global__ void k_rowloss2(const float2* __restrict__ part,
                           const float* __restrict__ logits,
                           const int* __restrict__ tgt, float* __restrict__ rl) {
  int row = blockIdx.x;
  int lane = threadIdx.x;
  float M = -1e30f, S = 0.f;
  for (int i = lane; i < NS2; i += 64) {
    float2 p = part[(size_t)row*NS2 + i];
    float mn = fmaxf(M, p.x);
    S = S*__expf(M - mn) + p.y*__expf(p.x - mn);
    M = mn;
  }
  #pragma unroll
  for (int o = 1; o < 64; o <<= 1) {
    float Mo = __shfl_xor(M, o);
    float So = __shfl_xor(S, o);
    float mn = fmaxf(M, Mo);
    S = S*__expf(M - mn) + So*__expf(Mo - mn);
    M = mn;
  }
  if (lane == 0)
    rl[row] = (logf(S) + M) - logits[(size_t)row*V_ + tgt[row]];
}

// ------- flash attention: T14 async-split, K/V double-buffered -------
__global__ __launch_bounds__(256) void k_fattn(
    const __hip_bfloat16* __restrict__ qkv, const int* __restrict__ doc,
    __hip_bfloat16* __restrict__ y)
{
  __shared__ __align__(16) short q_lds[QBLK*64];
  __shared__ __align__(16) short k_lds[2][KVB*64];
  __shared__ __align__(16) short vt_lds[2][64*KVB];
  __shared__ __align__(16) short p_lds[4][16*64];
  __shared__ int doc_lds[T_];
  const int t = threadIdx.x;
  const int lane = t & 63;
  const int w = t >> 6;
  const int q0 = (gridDim.x - 1 - blockIdx.x) * QBLK;
  const int h = blockIdx.y, b = blockIdx.z;
  const int lrow = lane & 15;
  const int lgrp = lane >> 4;
  const int crow = lgrp * 4;
  const int wbase = (t & 192) * 16;
  const short* qp = (const short*)qkv;

  auto stageK = [&](int kv0, int buf) {
    #pragma unroll
    for (int p = 0; p < 2; ++p) {
      int c = p*256 + t;
      int row = c >> 3;
      int colb = (c & 7) << 4;
      const char* src = (const char*)(qp + ((size_t)(b*T_ + kv0 + row))*QS3 + D_ + h*HD_)
                        + (colb ^ ((row & 7) << 4));
      gl_lds16(src, (char*)k_lds[buf] + p*4096 + wbase);
    }
  };

  #pragma unroll
  for (int p = 0; p < 2; ++p) {
    int c = p*256 + t;
    int row = c >> 3;
    int colb = (c & 7) << 4;
    const char* src = (const char*)(qp + ((size_t)(b*T_ + q0 + row))*QS3 + h*HD_)
                      + (colb ^ ((row & 7) << 4));
    gl_lds16(src, (char*)q_lds + p*4096 + wbase);
  }
  #pragma unroll
  for (int i = 0; i < 4; ++i) doc_lds[t + i*256] = doc[b*T_ + t + i*256];
  stageK(0, 0);
  s16x8 vc0, vc1;
  {
    int c0 = t, c1 = 256 + t;
    vc0 = *(const s16x8*)(qp + ((size_t)(b*T_ + (c0>>3)))*QS3 + 2*D_ + h*HD_ + (c0&7)*8);
    vc1 = *(const s16x8*)(qp + ((size_t)(b*T_ + (c1>>3)))*QS3 + 2*D_ + h*HD_ + (c1&7)*8);
  }
  __syncthreads();

  int docq[4];
  #pragma unroll
  for (int r = 0; r < 4; ++r)
    docq[r] = doc_lds[q0 + w*16 + crow + r];

  float m_r[4], l_r[4];
  #pragma unroll
  for (int r = 0; r < 4; ++r) { m_r[r] = -1e30f; l_r[r] = 0.f; }
  f32x4 o[4];
  #pragma unroll
  for (int fd = 0; fd < 4; ++fd) o[fd] = (f32x4){0.f,0.f,0.f,0.f};

  const int ntiles = q0/KVB + 1;
  for (int kt = 0; kt < ntiles; ++kt) {
    const int kv0 = kt * KVB;
    const int cur = kt & 1;
    const bool hn = (kt + 1 < ntiles);
    s16x8 vn0, vn1;
    if (hn) {
      stageK(kv0 + KVB, cur ^ 1);
      int c0 = t, c1 = 256 + t;
      vn0 = *(const s16x8*)(qp + ((size_t)(b*T_ + kv0 + KVB + (c0>>3)))*QS3 + 2*D_ + h*HD_ + (c0&7)*8);
      vn1 = *(const s16x8*)(qp + ((size_t)(b*T_ + kv0 + KVB + (c1>>3)))*QS3 + 2*D_ + h*HD_ + (c1&7)*8);
    }
    {
      int c0 = t, kvr0 = c0 >> 3, d00 = (c0 & 7)*8;
      #pragma unroll
      for (int j = 0; j < 8; ++j) {
        int d = d00 + j;
        int off = (d*128 + kvr0*2) ^ ((d & 7) << 4);
        *(short*)((char*)vt_lds[cur] + off) = vc0[j];
      }
      int c1 = 256 + t, kvr1 = c1 >> 3, d01 = (c1 & 7)*8;
      #pragma unroll
      for (int j = 0; j < 8; ++j) {
        int d = d01 + j;
        int off = (d*128 + kvr1*2) ^ ((d & 7) << 4);
        *(short*)((char*)vt_lds[cur] + off) = vc1[j];
      }
    }
    if (hn) asm volatile("s_waitcnt vmcnt(4)" ::: "memory");
    else    asm volatile("s_waitcnt vmcnt(0)" ::: "memory");
    __builtin_amdgcn_s_barrier();

    f32x4 sfr[4];
    #pragma unroll
    for (int fn = 0; fn < 4; ++fn) sfr[fn] = (f32x4){0.f,0.f,0.f,0.f};
    #pragma unroll
    for (int ks = 0; ks < 2; ++ks) {
      int arow = w*16 + lrow;
      s16x8 af = *(const s16x8*)((const char*)q_lds +
                 ((arow*128 + lgrp*16 + ks*64) ^ ((arow & 7) << 4)));
      #pragma unroll
      for (int fn = 0; fn < 4; ++fn) {
        int brow = fn*16 + lrow;
        s16x8 bf = *(const s16x8*)((const char*)k_lds[cur] +
                   ((brow*128 + lgrp*16 + ks*64) ^ ((brow & 7) << 4)));
        sfr[fn] = __builtin_amdgcn_mfma_f32_16x16x32_bf16(af, bf, sfr[fn], 0, 0, 0);
      }
    }
    int dk[4];
    #pragma unroll
    for (int fn = 0; fn < 4; ++fn) dk[fn] = doc_lds[kv0 + fn*16 + lrow];
    float rowmax[4] = {-1e30f, -1e30f, -1e30f, -1e30f};
    #pragma unroll
    for (int fn = 0; fn < 4; ++fn) {
      int col = kv0 + fn*16 + lrow;
      #pragma unroll
      for (int r = 0; r < 4; ++r) {
        int qrow = q0 + w*16 + crow + r;
        bool ok = (col <= qrow) && (dk[fn] == docq[r]);
        float v = ok ? sfr[fn][r] * 0.125f : -1e30f;
        sfr[fn][r] = v;
        rowmax[r] = fmaxf(rowmax[r], v);
      }
    }
    #pragma unroll
    for (int r = 0; r < 4; ++r) {
      float v = rowmax[r];
      #pragma unroll
      for (int off = 1; off < 16; off <<= 1) v = fmaxf(v, __shfl_xor(v, off));
      rowmax[r] = v;
    }
    float alpha[4], psum[4];
    #pragma unroll
    for (int r = 0; r < 4; ++r) {
      float mn = fmaxf(m_r[r], rowmax[r]);
      alpha[r] = __expf(m_r[r] - mn);
      m_r[r] = mn;
      psum[r] = 0.f;
    }
    #pragma unroll
    for (int fn = 0; fn < 4; ++fn) {
      #pragma unroll
      for (int r = 0; r < 4; ++r) {
        float sv = sfr[fn][r];
        float p = (sv < -5e29f) ? 0.f : __expf(sv - m_r[r]);
        psum[r] += p;
        int rl_ = crow + r;
        int off = (rl_*128 + (fn*16 + lrow)*2) ^ ((rl_ & 7) << 4);
        *(short*)((char*)p_lds[w] + off) = f2bf(p);
      }
    }
    #pragma unroll
    for (int r = 0; r < 4; ++r) {
      float v = psum[r];
      #pragma unroll
      for (int off = 1; off < 16; off <<= 1) v += __shfl_xor(v, off);
      l_r[r] = l_r[r]*alpha[r] + v;
    }
    #pragma unroll
    for (int fd = 0; fd < 4; ++fd)
      #pragma unroll
      for (int r = 0; r < 4; ++r)
        o[fd][r] *= alpha[r];
    #pragma unroll
    for (int ks = 0; ks < 2; ++ks) {
      s16x8 af = *(const s16x8*)((const char*)p_lds[w] +
                 ((lrow*128 + lgrp*16 + ks*64) ^ ((lrow & 7) << 4)));
      #pragma unroll
      for (int fd = 0; fd < 4; ++fd) {
        int brow = fd*16 + lrow;
        s16x8 bf = *(const s16x8*)((const char*)vt_lds[cur] +
                   ((brow*128 + lgrp*16 + ks*64) ^ ((brow & 7) << 4)));
        o[fd] = __builtin_amdgcn_mfma_f32_16x16x32_bf16(af, bf, o[fd], 0, 0, 0);
      }
    }
    __builtin_amdgcn_s_barrier();
    vc0 = vn0; vc1 = vn1;
  }
  #pragma unroll
  for (int r = 0; r < 4; ++r) {
    float inv = 1.f / l_r[r];
    int rowg = b*T_ + q0 + w*16 + crow + r;
    #pragma unroll
    for (int fd = 0; fd < 4; ++fd) {
      int col = h*HD_ + fd*16 + lrow;
      y[(size_t)rowg*D_ + col] = __float2bfloat16(o[fd][r] * inv);
    }
  }
}

// ---------------- fallback per-row log-softmax ----------------
__global__ void k_rowloss(const float* __restrict__ logits,
                          const int* __restrict__ tgt, float* __restrict__ rl) {
  __shared__ float red[4];
  int row = blockIdx.x;
  const float* lr = logits + (size_t)row * V_;
  int tid = threadIdx.x;
  float m = -1e30f;
  for (int v = tid; v < V_; v += 256) m = fmaxf(m, lr[v]);
  #pragma unroll
  for (int o = 1; o < 64; o <<= 1) m = fmaxf(m, __shfl_xor(m, o));
  if ((tid & 63) == 0) red[tid >> 6] = m;
  __syncthreads();
  m = fmaxf(fmaxf(red[0], red[1]), fmaxf(red[2], red[3]));
  __syncthreads();
  float s = 0.f;
  for (int v = tid; v < V_; v += 256) s += __expf(lr[v] - m);
  #pragma unroll
  for (int o = 1; o < 64; o <<= 1) s += __shfl_xor(s, o);
  if ((tid & 63) == 0) red[tid >> 6] = s;
  __syncthreads();
  if (tid == 0) {
    s = red[0]+red[1]+red[2]+red[3];
    rl[row] = (logf(s) + m) - lr[tgt[row]];
  }
}

// ---------------- final loss = mean(rl) ----------------
__global__ void k_loss(const float* __restrict__ rl, float* __restrict__ out) {
  __shared__ float red[4];
  int tid = threadIdx.x;
  float s = 0.f;
  for (int i = tid; i < NTOK; i += 256) s += rl[i];
  #pragma unroll
  for (int o = 1; o < 64; o <<= 1) s += __shfl_xor(s, o);
  if ((tid & 63) == 0) red[tid >> 6] = s;
  __syncthreads();
  if (tid == 0) {
    s = red[0]+red[1]+red[2]+red[3];
    out[0] = s / (float)NTOK;
  }
}

extern "C" void kernel_launch(void* const* d_in, const int* in_sizes, int n_in,
                              void* d_out, int out_size, void* d_ws, size_t ws_size,
                              hipStream_t stream) {
  const int*   idx   = (const int*)d_in[0];
  const int*   tgt   = (const int*)d_in[1];
  const float* tok   = (const float*)d_in[2];
  const float* pos   = (const float*)d_in[3];
  const float* ln1_g = (const float*)d_in[4];
  const float* ln1_b = (const float*)d_in[5];
  const float* ln2_g = (const float*)d_in[6];
  const float* ln2_b = (const float*)d_in[7];
  const float* W_qkv = (const float*)d_in[8];
  const float* b_qkv = (const float*)d_in[9];
  const float* W_proj= (const float*)d_in[10];
  const float* b_proj= (const float*)d_in[11];
  const float* W_fc1 = (const float*)d_in[12];
  const float* b_fc1 = (const float*)d_in[13];
  const float* W_fc2 = (const float*)d_in[14];
  const float* b_fc2 = (const float*)d_in[15];
  const float* lnf_g = (const float*)d_in[16];
  const float* lnf_b = (const float*)d_in[17];

  float* out = (float*)d_out;

  char* ob = (char*)d_out;
  float*           x    = (float*)(ob + 0);
  __hip_bfloat16*  qkv  = (__hip_bfloat16*)(ob + (size_t)6291456);
  __hip_bfloat16*  y    = (__hip_bfloat16*)(ob + (size_t)15728640);
  __hip_bfloat16*  tff  = (__hip_bfloat16*)(ob + (size_t)18874368);
  __hip_bfloat16*  WTq  = (__hip_bfloat16*)(ob + (size_t)40894464);
  __hip_bfloat16*  WTp  = (__hip_bfloat16*)(ob + (size_t)62128128);
  __hip_bfloat16*  WT1  = (__hip_bfloat16*)(ob + (size_t)69206016);
  __hip_bfloat16*  WT2  = (__hip_bfloat16*)(ob + (size_t)97517568);  // ends 125,829,120

  char* wb = (char*)d_ws;
  __hip_bfloat16* h    = (__hip_bfloat16*)(wb + 0);
  int*    doc  = (int*)  (wb + (size_t)3145728);
  float*  rl   = (float*)(wb + (size_t)3153920);
  float2* part = (float2*)(wb + (size_t)3162112);
  __hip_bfloat16* tokh = (__hip_bfloat16*)(wb + (size_t)9601024);
  const size_t ws_need_part = (size_t)9601024;
  const size_t ws_need_tokh = (size_t)9601024 + 77194752 + 131072;
  const bool fused_loss = (ws_size >= ws_need_part);
  const bool use_tokh   = (ws_size >= ws_need_tokh);

  dim3 tb(32, 8);
  k_wt<<<dim3(2304/32, 768/32, L_), tb, 0, stream>>>(W_qkv,  WTq,  768, 2304);
  k_wt<<<dim3( 768/32, 768/32, L_), tb, 0, stream>>>(W_proj, WTp,  768,  768);
  k_wt<<<dim3(3072/32, 768/32, L_), tb, 0, stream>>>(W_fc1,  WT1,  768, 3072);
  k_wt<<<dim3( 768/32,3072/32, L_), tb, 0, stream>>>(W_fc2,  WT2, 3072,  768);
  if (use_tokh)
    k_cast_tok<<<2048, 256, 0, stream>>>(tok, tokh, (long)V_*768/8);

  k_embed<<<(NTOK*D_ + 255)/256, 256, 0, stream>>>(idx, tok, pos, x);
  k_docid<<<1, 64, 0, stream>>>(idx, doc);

  for (int l = 0; l < L_; ++l) {
    k_ln<<<NTOK, 64, 0, stream>>>(x, ln1_g + l*D_, ln1_b + l*D_, h);
    k_mfma_nt<<<dim3(2304/64, NTOK/128), 256, 0, stream>>>(
        h, WTq + (size_t)l*2304*768, nullptr, b_qkv + (size_t)l*2304, nullptr,
        nullptr, qkv, NTOK, 2304, 768, 0);
    k_fattn<<<dim3(T_/QBLK, H_, B_), 256, 0, stream>>>(qkv, doc, y);
    k_mfma_nt64<<<dim3(768/64, NTOK/64), 256, 0, stream>>>(
        y, WTp + (size_t)l*768*768, b_proj + (size_t)l*768, x, x,
        NTOK, 768, 768);
    k_ln<<<NTOK, 64, 0, stream>>>(x, ln2_g + l*D_, ln2_b + l*D_, h);
    k_mfma_nt<<<dim3(3072/64, NTOK/128), 256, 0, stream>>>(
        h, WT1 + (size_t)l*3072*768, nullptr, b_fc1 + (size_t)l*3072, nullptr,
        nullptr, tff, NTOK, 3072, 768, 1);
    k_mfma_nt64<<<dim3(768/64, NTOK/64), 256, 0, stream>>>(
        tff, WT2 + (size_t)l*768*3072, b_fc2 + (size_t)l*768, x, x,
        NTOK, 768, 3072);
  }
  k_ln<<<NTOK, 64, 0, stream>>>(x, lnf_g, lnf_b, h);

  if (fused_loss) {
    k_logits<<<NS2*16, 512, 0, stream>>>(
        h, use_tokh ? tokh : nullptr, tok, out, part);
    k_rowloss2<<<NTOK, 64, 0, stream>>>(part, out, tgt, rl);
  } else {
    k_mfma_nt<<<dim3((V_ + 63)/64, NTOK/128), 256, 0, stream>>>(
        h, nullptr, tok, nullptr, nullptr, out, nullptr, NTOK, V_, 768, 0);
    k_rowloss<<<NTOK, 256, 0, stream>>>(out, tgt, rl);
  }
  k_loss<<<1, 256, 0, stream>>>(rl, out + (size_t)NTOK*V_);
}